// Round 2
// baseline (134.924 us; speedup 1.0000x reference)
//
#include <hip/hip_runtime.h>

#define BB 192          // B
#define NN 384          // 2B
#define DD 512          // D
#define EPSF 1e-8f
#define MARGINF 0.1f

// ws layout (floats):
// [0, NN*DD)            : normalized embeddings
// [NN*DD, NN*DD+NN)     : sq[i] = dot(emb_i, emb_i)
// [NN*DD+NN, +2)        : accum[0]=sum, accum[1]=count

__global__ void normalize_kernel(const float* __restrict__ o1,
                                 const float* __restrict__ o2,
                                 float* __restrict__ emb,
                                 float* __restrict__ sq,
                                 float* __restrict__ accum) {
    int i = blockIdx.x;
    const float* row = (i < BB) ? (o1 + (size_t)i * DD)
                                : (o2 + (size_t)(i - BB) * DD);
    int t = threadIdx.x;               // 256 threads, 2 floats each
    float2 v = reinterpret_cast<const float2*>(row)[t];
    float ss = v.x * v.x + v.y * v.y;
    __shared__ float red[4];
    for (int off = 32; off >= 1; off >>= 1) ss += __shfl_xor(ss, off);
    int wave = t >> 6, lane = t & 63;
    if (lane == 0) red[wave] = ss;
    __syncthreads();
    float tot = red[0] + red[1] + red[2] + red[3];
    float n = fmaxf(sqrtf(tot), 1e-12f);
    float inv = 1.0f / n;
    float2 e; e.x = v.x * inv; e.y = v.y * inv;
    reinterpret_cast<float2*>(emb + (size_t)i * DD)[t] = e;
    // sq of the normalized row (matches reference's diag(emb@emb.T))
    float ss2 = e.x * e.x + e.y * e.y;
    for (int off = 32; off >= 1; off >>= 1) ss2 += __shfl_xor(ss2, off);
    __syncthreads();
    if (lane == 0) red[wave] = ss2;
    __syncthreads();
    if (t == 0) {
        sq[i] = red[0] + red[1] + red[2] + red[3];
        if (i == 0) { accum[0] = 0.0f; accum[1] = 0.0f; }
    }
}

__global__ void triplet_kernel(const float* __restrict__ emb,
                               const float* __restrict__ sq,
                               const float* __restrict__ weight,
                               float* __restrict__ accum) {
    int i = blockIdx.x;
    int t = threadIdx.x;
    int wave = t >> 6, lane = t & 63;

    __shared__ float4 si[DD / 4];      // anchor row, 2 KB
    __shared__ float sdpos;
    __shared__ float ssum[4];
    __shared__ float scnt[4];

    const float4* erow = reinterpret_cast<const float4*>(emb + (size_t)i * DD);
    if (t < DD / 4) si[t] = erow[t];
    __syncthreads();

    float sq_i = sq[i];
    int p = (i + BB) % NN;             // unique positive partner

    if (wave == 0) {
        const float4* ep = reinterpret_cast<const float4*>(emb + (size_t)p * DD);
        float4 a0 = si[lane],       b0 = ep[lane];
        float4 a1 = si[lane + 64],  b1 = ep[lane + 64];
        float acc = a0.x * b0.x + a0.y * b0.y + a0.z * b0.z + a0.w * b0.w
                  + a1.x * b1.x + a1.y * b1.y + a1.z * b1.z + a1.w * b1.w;
        for (int off = 32; off >= 1; off >>= 1) acc += __shfl_xor(acc, off);
        if (lane == 0) {
            float d2 = fmaxf(0.0f, sq[p] - 2.0f * acc + sq_i);
            sdpos = (d2 > 0.0f) ? sqrtf(d2) : 0.0f;
        }
    }
    __syncthreads();
    float dpos = sdpos;

    int ib = (i >= BB) ? i - BB : i;
    const float* wrow = weight + (size_t)ib * BB;

    float lsum = 0.0f, lcnt = 0.0f;
    for (int k = wave; k < NN; k += 4) {     // wave-uniform loop
        int kb = (k >= BB) ? k - BB : k;
        if (kb == ib) continue;              // same label -> masked out
        const float4* ek = reinterpret_cast<const float4*>(emb + (size_t)k * DD);
        float4 a0 = si[lane],       b0 = ek[lane];
        float4 a1 = si[lane + 64],  b1 = ek[lane + 64];
        float acc = a0.x * b0.x + a0.y * b0.y + a0.z * b0.z + a0.w * b0.w
                  + a1.x * b1.x + a1.y * b1.y + a1.z * b1.z + a1.w * b1.w;
        for (int off = 32; off >= 1; off >>= 1) acc += __shfl_xor(acc, off);
        if (lane == 0) {
            float d2 = fmaxf(0.0f, sq[k] - 2.0f * acc + sq_i);
            float dik = (d2 > 0.0f) ? sqrtf(d2) : 0.0f;
            float tl = dpos - dik + MARGINF;
            if (tl > 0.0f) {
                float v = tl * wrow[kb];
                lsum += v;
                if (v > EPSF) lcnt += 1.0f;
            }
        }
    }
    if (lane == 0) { ssum[wave] = lsum; scnt[wave] = lcnt; }
    __syncthreads();
    if (t == 0) {
        atomicAdd(&accum[0], ssum[0] + ssum[1] + ssum[2] + ssum[3]);
        atomicAdd(&accum[1], scnt[0] + scnt[1] + scnt[2] + scnt[3]);
    }
}

__global__ void finalize_kernel(const float* __restrict__ accum,
                                float* __restrict__ out) {
    if (threadIdx.x == 0 && blockIdx.x == 0)
        out[0] = accum[0] / (accum[1] + EPSF);
}

extern "C" void kernel_launch(void* const* d_in, const int* in_sizes, int n_in,
                              void* d_out, int out_size, void* d_ws, size_t ws_size,
                              hipStream_t stream) {
    const float* o1 = (const float*)d_in[0];
    const float* o2 = (const float*)d_in[1];
    const float* w  = (const float*)d_in[2];
    float* out = (float*)d_out;

    float* ws    = (float*)d_ws;
    float* emb   = ws;
    float* sq    = ws + (size_t)NN * DD;
    float* accum = sq + NN;

    normalize_kernel<<<NN, 256, 0, stream>>>(o1, o2, emb, sq, accum);
    triplet_kernel<<<NN, 256, 0, stream>>>(emb, sq, w, accum);
    finalize_kernel<<<1, 64, 0, stream>>>(accum, out);
}

// Round 3
// 84.047 us; speedup vs baseline: 1.6053x; 1.6053x over previous
//
#include <hip/hip_runtime.h>

#define BB 192          // B
#define NN 384          // 2B
#define DD 512          // D
#define EPSF 1e-8f
#define MARGINF 0.1f
#define BKT 128         // K-tile staged in LDS
#define PAD 34          // k-major LDS row stride (float2 reads conflict-free, 8B aligned)

// ws layout (floats):
// [0, NN)        : ninv[i] = 1/||raw row i||
// [NN, NN+2)     : accum[0]=sum, accum[1]=count
// [512, ...)     : G[z][NN*NN] raw gram slabs (z = 0..KS-1)

__global__ void norms_kernel(const float* __restrict__ o1,
                             const float* __restrict__ o2,
                             float* __restrict__ ninv,
                             float* __restrict__ accum) {
    int w = threadIdx.x >> 6, lane = threadIdx.x & 63;
    int r = blockIdx.x * 4 + w;
    const float4* src = reinterpret_cast<const float4*>(
        (r < BB) ? o1 + (size_t)r * DD : o2 + (size_t)(r - BB) * DD);
    float4 v0 = src[lane], v1 = src[lane + 64];
    float ss = v0.x*v0.x + v0.y*v0.y + v0.z*v0.z + v0.w*v0.w
             + v1.x*v1.x + v1.y*v1.y + v1.z*v1.z + v1.w*v1.w;
    for (int off = 32; off >= 1; off >>= 1) ss += __shfl_xor(ss, off);
    if (lane == 0) ninv[r] = 1.0f / fmaxf(sqrtf(ss), 1e-12f);
    if (blockIdx.x == 0 && threadIdx.x == 0) { accum[0] = 0.0f; accum[1] = 0.0f; }
}

// 32x32 output tile per block, 2x2 per thread, k-major LDS so the inner loop
// is pure float2 LDS reads + 4 FMAs per kk (no shuffles, all lanes busy).
__global__ __launch_bounds__(256) void gram_kernel(const float* __restrict__ o1,
                                                   const float* __restrict__ o2,
                                                   float* __restrict__ Gout,
                                                   int klen) {
    __shared__ float As[BKT][PAD];
    __shared__ float Bs[BKT][PAD];
    int t = threadIdx.x;
    int bi = blockIdx.x, bk = blockIdx.y, bz = blockIdx.z;
    int ai0 = bi * 32, ki0 = bk * 32;
    const float4* Asrc = reinterpret_cast<const float4*>(
        (bi < 6) ? o1 + (size_t)ai0 * DD : o2 + (size_t)(ai0 - BB) * DD);
    const float4* Bsrc = reinterpret_cast<const float4*>(
        (bk < 6) ? o1 + (size_t)ki0 * DD : o2 + (size_t)(ki0 - BB) * DD);
    int tx = t & 15, ty = t >> 4;
    float acc00 = 0.f, acc01 = 0.f, acc10 = 0.f, acc11 = 0.f;
    int kbase4 = bz * (klen >> 2);        // float4 units
    int nkt = klen / BKT;
    for (int kt = 0; kt < nkt; ++kt) {
        int k04 = kbase4 + kt * (BKT / 4);
        __syncthreads();                  // protect previous iter's reads
        #pragma unroll
        for (int j = 0; j < 4; ++j) {
            int id = j * 256 + t;
            int row = id >> 5, c4 = id & 31;
            float4 va = Asrc[(size_t)row * (DD / 4) + k04 + c4];
            float4 vb = Bsrc[(size_t)row * (DD / 4) + k04 + c4];
            int kk = c4 << 2;
            As[kk][row] = va.x; As[kk + 1][row] = va.y;
            As[kk + 2][row] = va.z; As[kk + 3][row] = va.w;
            Bs[kk][row] = vb.x; Bs[kk + 1][row] = vb.y;
            Bs[kk + 2][row] = vb.z; Bs[kk + 3][row] = vb.w;
        }
        __syncthreads();
        #pragma unroll 8
        for (int kk = 0; kk < BKT; ++kk) {
            float2 a = *reinterpret_cast<const float2*>(&As[kk][ty * 2]);
            float2 b = *reinterpret_cast<const float2*>(&Bs[kk][tx * 2]);
            acc00 += a.x * b.x; acc01 += a.x * b.y;
            acc10 += a.y * b.x; acc11 += a.y * b.y;
        }
    }
    float* g = Gout + (size_t)bz * NN * NN;
    int gi = ai0 + ty * 2, gk = ki0 + tx * 2;
    g[(size_t)gi * NN + gk]       = acc00;
    g[(size_t)gi * NN + gk + 1]   = acc01;
    g[(size_t)(gi + 1) * NN + gk]     = acc10;
    g[(size_t)(gi + 1) * NN + gk + 1] = acc11;
}

__global__ void loss_kernel(const float* __restrict__ G,
                            const float* __restrict__ ninv,
                            const float* __restrict__ weight,
                            float* __restrict__ accum,
                            int nslab) {
    int i = blockIdx.x;
    int t = threadIdx.x;
    int w = t >> 6, lane = t & 63;
    int ib = (i < BB) ? i : i - BB;
    int p  = (i < BB) ? i + BB : i - BB;
    float ninv_i = ninv[i];
    const float* Gi  = G + (size_t)i * NN;
    const float* Gi2 = Gi + (size_t)NN * NN;

    float gp = Gi[p] + ((nslab == 2) ? Gi2[p] : 0.0f);
    float cosp = gp * ninv_i * ninv[p];
    float d2p = fmaxf(0.0f, 2.0f - 2.0f * cosp);
    float dpos = (d2p > 0.0f) ? sqrtf(d2p) : 0.0f;

    float lsum = 0.0f, lcnt = 0.0f;
    for (int k = t; k < NN; k += 256) {
        int kb = (k < BB) ? k : k - BB;
        if (kb == ib) continue;           // same label (k==i or k==p)
        float g = Gi[k] + ((nslab == 2) ? Gi2[k] : 0.0f);
        float c = g * ninv_i * ninv[k];
        float d2 = fmaxf(0.0f, 2.0f - 2.0f * c);
        float dik = (d2 > 0.0f) ? sqrtf(d2) : 0.0f;
        float tl = dpos - dik + MARGINF;
        if (tl > 0.0f) {
            float v = tl * weight[(size_t)ib * BB + kb];
            lsum += v;
            if (v > EPSF) lcnt += 1.0f;
        }
    }
    for (int off = 32; off >= 1; off >>= 1) {
        lsum += __shfl_xor(lsum, off);
        lcnt += __shfl_xor(lcnt, off);
    }
    __shared__ float ssum[4], scnt[4];
    if (lane == 0) { ssum[w] = lsum; scnt[w] = lcnt; }
    __syncthreads();
    if (t == 0) {
        atomicAdd(&accum[0], ssum[0] + ssum[1] + ssum[2] + ssum[3]);
        atomicAdd(&accum[1], scnt[0] + scnt[1] + scnt[2] + scnt[3]);
    }
}

__global__ void finalize_kernel(const float* __restrict__ accum,
                                float* __restrict__ out) {
    if (threadIdx.x == 0 && blockIdx.x == 0)
        out[0] = accum[0] / (accum[1] + EPSF);
}

extern "C" void kernel_launch(void* const* d_in, const int* in_sizes, int n_in,
                              void* d_out, int out_size, void* d_ws, size_t ws_size,
                              hipStream_t stream) {
    const float* o1 = (const float*)d_in[0];
    const float* o2 = (const float*)d_in[1];
    const float* w  = (const float*)d_in[2];
    float* out = (float*)d_out;

    float* ws_f  = (float*)d_ws;
    float* ninv  = ws_f;
    float* accum = ws_f + NN;
    float* G     = ws_f + 512;

    // K-split halves the per-block critical path but needs 2 gram slabs.
    size_t need2 = (size_t)(512 + 2 * NN * NN) * sizeof(float);
    int KS = (ws_size >= need2) ? 2 : 1;

    norms_kernel<<<NN / 4, 256, 0, stream>>>(o1, o2, ninv, accum);
    gram_kernel<<<dim3(12, 12, KS), 256, 0, stream>>>(o1, o2, G, DD / KS);
    loss_kernel<<<NN, 256, 0, stream>>>(G, ninv, w, accum, KS);
    finalize_kernel<<<1, 64, 0, stream>>>(accum, out);
}